// Round 1
// 248.950 us; speedup vs baseline: 1.0206x; 1.0206x over previous
//
#include <hip/hip_runtime.h>

#define DIN   2048
#define DOUT  2048
#define NP    16
#define TPW   8    // tokens per wave
#define WPB   2    // waves per block (independent; no cross-wave handoff)

// ws layout (byte offsets)
#define HDR_OFF   0                      // 2 floats: w1, w2
#define WK4_OFF   256                    // 8192 u32 (32 KB) ternary Wk
#define WV4_OFF   (WK4_OFF + 32768)      // 2048 uint4 (32 KB) ternary Wv rows

static __device__ __forceinline__ int dot4(unsigned a, unsigned b, int c) {
#if defined(__has_builtin) && __has_builtin(__builtin_amdgcn_sdot4)
  return __builtin_amdgcn_sdot4((int)a, (int)b, c, false);
#else
  c += (int)(signed char)(a & 0xffu)        * (int)(signed char)(b & 0xffu);
  c += (int)(signed char)((a >> 8) & 0xffu) * (int)(signed char)((b >> 8) & 0xffu);
  c += (int)(signed char)((a >> 16) & 0xffu)* (int)(signed char)((b >> 16) & 0xffu);
  c += (int)(signed char)(a >> 24)          * (int)(signed char)(b >> 24);
  return c;
#endif
}

// fma-magic int8 quantize: low byte of (f*xs + 1.5*2^23) = round-to-even(f*xs)
static __device__ __forceinline__ unsigned qmagic(float f, float xs) {
  return __float_as_uint(fmaf(f, xs, 12582912.0f)) & 0xffu;
}

// reference-exact double-rounded quantize (epilogue 16-value re-quant)
static __device__ __forceinline__ unsigned q8(float f, float xs) {
  float t = f * xs;
  float r = rintf(t);
  r = fmaxf(-128.0f, fminf(127.0f, r));
  return ((unsigned)(int)r) & 0xffu;
}

// ---------------------------------------------------------------------------
// k_prep: fused reduce+pack, 40 blocks. Every block recomputes its matrix's
// abs-sum with the SAME op order as the old k_reduce/k_pack pair (8 virtual
// partials, per-partial 256-tree, then sequential sum) -> bitwise-identical sc.
// Blocks 0-31 pack Wk slices, 32-39 pack Wv rows.
// ---------------------------------------------------------------------------
__global__ __launch_bounds__(256) void k_prep(
    const float* __restrict__ Wk, const float* __restrict__ Wv,
    float* __restrict__ hdr, unsigned* __restrict__ wk4, unsigned* __restrict__ wv4)
{
  __shared__ float red[8][256];
  const int tid = threadIdx.x, b = blockIdx.x;
  const int isV = (b >= 32);
  const float4* W = (const float4*)(isV ? Wv : Wk);

  float4 own = make_float4(0.f, 0.f, 0.f, 0.f);
#pragma unroll
  for (int lb = 0; lb < 8; ++lb) {
    float s = 0.f;
#pragma unroll
    for (int i = 0; i < 4; ++i) {
      float4 v = W[lb * 1024 + i * 256 + tid];
      if (!isV && (lb * 4 + i) == b) own = v;   // capture own pack slice
      s += fabsf(v.x) + fabsf(v.y) + fabsf(v.z) + fabsf(v.w);
    }
    red[lb][tid] = s;
  }
  __syncthreads();
#pragma unroll 1
  for (int o = 128; o > 0; o >>= 1) {
    if (tid < o) {
#pragma unroll
      for (int lb = 0; lb < 8; ++lb) red[lb][tid] += red[lb][tid + o];
    }
    __syncthreads();
  }
  float sum = 0.f;
#pragma unroll
  for (int lb = 0; lb < 8; ++lb) sum += red[lb][0];
  const float sc = fmaxf(sum * (1.0f / 32768.0f), 1e-5f);
  if (tid == 0 && (b == 0 || b == 32)) hdr[isV] = sc;

  if (!isV) {
    const int c = b * 256 + tid;          // [0, 8192)
    unsigned pk = 0; const float* wp = &own.x;
#pragma unroll
    for (int j = 0; j < 4; ++j) {
      float r = rintf(wp[j] / sc);
      r = fmaxf(-1.0f, fminf(1.0f, r));
      pk |= (((unsigned)(int)r) & 0xffu) << (8 * j);
    }
    wk4[c] = pk;
  } else {
    const int o = (b - 32) * 256 + tid;   // row [0, 2048)
    unsigned u[4];
#pragma unroll
    for (int cc = 0; cc < 4; ++cc) {
      float4 w = ((const float4*)Wv)[o * 4 + cc];   // L2-hot re-read
      const float* wp = &w.x;
      unsigned pk = 0;
#pragma unroll
      for (int r = 0; r < 4; ++r) {
        float q = rintf(wp[r] / sc);
        q = fmaxf(-1.0f, fminf(1.0f, q));
        pk |= (((unsigned)(int)q) & 0xffu) << (8 * r);
      }
      u[cc] = pk;
    }
    ((uint4*)wv4)[o] = make_uint4(u[0], u[1], u[2], u[3]);
  }
}

// ---------------------------------------------------------------------------
// k_main: fused kA+kB. Block = 2 independent waves; each wave owns 8 tokens.
// Phase A: Wk ternary table register-resident (tab[128]); per token absmax ->
// int8 quant -> 16x8 sdot4 -> reduce-scatter; per 4-token group one epilogue
// (gelu, L2-norm, re-quant) whose q2/s2 goes to wave-private LDS (no global
// round-trip). a[2][8] double-buffer: token i+1's loads are issued under
// token i's dot/reduce work (all buffer indices static -> registers).
// Phase B: SAME tab[128] array reloaded with Wv rows (dead-range reuse keeps
// peak VGPR ~ one table), then 8 tokens x 32 sdot4 -> float4 stores.
// ---------------------------------------------------------------------------
__global__ __launch_bounds__(128, 2) void k_main(
    const float* __restrict__ x, const float* __restrict__ hdr,
    const unsigned* __restrict__ wk4, const unsigned* __restrict__ wv4,
    float* __restrict__ out)
{
  const int l  = threadIdx.x & 63;
  const int ws = threadIdx.x >> 6;                       // wave slot 0/1
  const long t0 = ((long)blockIdx.x * WPB + ws) * TPW;   // first token of wave

  __shared__ uint4 qls[WPB][TPW];
  __shared__ float sls[WPB][TPW];

  const float w1 = hdr[0], w2 = hdr[1];
  const float4* xf = (const float4*)x;

  // ---- phase A: Wk table ----
  unsigned tab[128];
#pragma unroll
  for (int p = 0; p < 16; ++p)
#pragma unroll
    for (int c = 0; c < 8; ++c) tab[p * 8 + c] = wk4[p * 512 + c * 64 + l];

  float4 a[2][8];
#pragma unroll
  for (int c = 0; c < 8; ++c) a[0][c] = xf[t0 * 512 + c * 64 + l];

#pragma unroll 1
  for (int g = 0; g < TPW / 4; ++g) {
    int   sv[4];
    float s1[4];
#pragma unroll
    for (int ii = 0; ii < 4; ++ii) {                     // unrolled: static idx
      const long tok = t0 + g * 4 + ii;

      // absmax over this token (full wave)
      float mx = 0.0f;
#pragma unroll
      for (int c = 0; c < 8; ++c) {
        float4 v = a[ii & 1][c];
        mx = fmaxf(mx, fabsf(v.x)); mx = fmaxf(mx, fabsf(v.y));
        mx = fmaxf(mx, fabsf(v.z)); mx = fmaxf(mx, fabsf(v.w));
      }
#pragma unroll
      for (int d = 1; d < 64; d <<= 1) mx = fmaxf(mx, __shfl_xor(mx, d, 64));
      const float mcl = fmaxf(mx, 1e-5f);
      const float xs  = 127.0f / mcl;
      s1[ii] = w1 / xs;

      // quantize (|f*xs| <= 127 exactly, no clamp needed)
      unsigned qp[8];
#pragma unroll
      for (int c = 0; c < 8; ++c) {
        float4 v = a[ii & 1][c];
        qp[c] = qmagic(v.x, xs) | (qmagic(v.y, xs) << 8)
              | (qmagic(v.z, xs) << 16) | (qmagic(v.w, xs) << 24);
      }

      // prefetch next token into the other buffer (hides HBM latency
      // under the dot + reduce-scatter work below)
      if (g * 4 + ii < TPW - 1) {
#pragma unroll
        for (int c = 0; c < 8; ++c)
          a[(ii + 1) & 1][c] = xf[(tok + 1) * 512 + c * 64 + l];
      }

      // 16 integer dot rows (partial over this lane's 32 k's)
      int acc[16];
#pragma unroll
      for (int p = 0; p < 16; ++p) {
        int d = 0;
#pragma unroll
        for (int c = 0; c < 8; ++c) d = dot4(qp[c], tab[p * 8 + c], d);
        acc[p] = d;
      }

      // recursive-halving reduce-scatter, identity perm (p = l&15)
#pragma unroll
      for (int b = 0; b < 4; ++b) {
        const int lb = (l >> b) & 1;
#pragma unroll
        for (int j = 0; j < 8; ++j) {
          if (j < (8 >> b)) {
            int keep = lb ? acc[2 * j + 1] : acc[2 * j];
            int send = lb ? acc[2 * j]     : acc[2 * j + 1];
            acc[j] = keep + __shfl_xor(send, 1 << b, 64);
          }
        }
      }
      sv[ii] = acc[0];
    }

    // ---- group epilogue: route 4 token slots over lane bits 4/5 ----
    const int lb4 = (l >> 4) & 1, lb5 = (l >> 5) & 1;
    int r0 = (lb4 ? sv[1] : sv[0]) + __shfl_xor(lb4 ? sv[0] : sv[1], 16, 64);
    int r1 = (lb4 ? sv[3] : sv[2]) + __shfl_xor(lb4 ? sv[2] : sv[3], 16, 64);
    int rr = (lb5 ? r1 : r0) + __shfl_xor(lb5 ? r0 : r1, 32, 64);
    float s1a = lb4 ? s1[1] : s1[0];
    float s1b = lb4 ? s1[3] : s1[2];
    const float s1sel = lb5 ? s1b : s1a;

    const float fa = (float)rr * s1sel;
    const float gv = 0.5f * fa * (1.0f + erff(fa * 0.70710678118654752f));
    float ss = gv * gv;
    ss += __shfl_xor(ss, 1, 64); ss += __shfl_xor(ss, 2, 64);
    ss += __shfl_xor(ss, 4, 64); ss += __shfl_xor(ss, 8, 64);
    const float rn = fmaxf(sqrtf(ss), 1e-12f);
    const float gn = gv * (4.0f / rn);
    float am = fabsf(gn);
    {
      float o;
      o = __shfl_xor(am, 1, 64); am = fmaxf(am, o);
      o = __shfl_xor(am, 2, 64); am = fmaxf(am, o);
      o = __shfl_xor(am, 4, 64); am = fmaxf(am, o);
      o = __shfl_xor(am, 8, 64); am = fmaxf(am, o);
    }
    const float mc2 = fmaxf(am, 1e-5f);
    const float xs2 = 127.0f / mc2;
    const float s2  = w2 / xs2;

    unsigned sh = q8(gn, xs2) << ((l & 3) * 8);
    sh |= (unsigned)__shfl_xor((int)sh, 1, 64);
    sh |= (unsigned)__shfl_xor((int)sh, 2, 64);
    const unsigned wa = (unsigned)__shfl_xor((int)sh, 4, 64);
    const unsigned wb = (unsigned)__shfl_xor((int)sh, 8, 64);
    const unsigned wc = (unsigned)__shfl_xor((int)sh, 12, 64);
    if ((l & 15) == 0) {
      qls[ws][g * 4 + (l >> 4)] = make_uint4(sh, wa, wb, wc);
      sls[ws][g * 4 + (l >> 4)] = s2;
    }
  }

  // ---- phase B: reload the SAME table array with Wv rows ----
#pragma unroll
  for (int m = 0; m < 8; ++m)
#pragma unroll
    for (int j = 0; j < 4; ++j) {
      uint4 t = ((const uint4*)wv4)[m * 256 + l * 4 + j];
      tab[(m * 4 + j) * 4 + 0] = t.x; tab[(m * 4 + j) * 4 + 1] = t.y;
      tab[(m * 4 + j) * 4 + 2] = t.z; tab[(m * 4 + j) * 4 + 3] = t.w;
    }

  // formal LDS write->read ordering (cheap: once per kernel)
  __syncthreads();

  for (int i = 0; i < TPW; ++i) {
    const long tok = t0 + i;
    const uint4 q  = qls[ws][i];
    const float s2 = sls[ws][i];
#pragma unroll
    for (int m = 0; m < 8; ++m) {
      float h[4];
#pragma unroll
      for (int j = 0; j < 4; ++j) {
        int d = dot4(q.x, tab[(m * 4 + j) * 4 + 0], 0);
        d = dot4(q.y, tab[(m * 4 + j) * 4 + 1], d);
        d = dot4(q.z, tab[(m * 4 + j) * 4 + 2], d);
        d = dot4(q.w, tab[(m * 4 + j) * 4 + 3], d);
        h[j] = (float)d * s2;
      }
      *(float4*)(out + (size_t)tok * 2048 + m * 256 + l * 4) =
          make_float4(h[0], h[1], h[2], h[3]);
    }
  }
}

extern "C" void kernel_launch(void* const* d_in, const int* in_sizes, int n_in,
                              void* d_out, int out_size, void* d_ws, size_t ws_size,
                              hipStream_t stream) {
  const float* x  = (const float*)d_in[0];
  const float* Wk = (const float*)d_in[1];
  const float* Wv = (const float*)d_in[2];

  const int tokens = in_sizes[0] / DIN;  // 16384

  char* ws = (char*)d_ws;
  float*    hdr = (float*)(ws + HDR_OFF);
  unsigned* wk4 = (unsigned*)(ws + WK4_OFF);
  unsigned* wv4 = (unsigned*)(ws + WV4_OFF);

  k_prep<<<40, 256, 0, stream>>>(Wk, Wv, hdr, wk4, wv4);
  k_main<<<tokens / (TPW * WPB), 128, 0, stream>>>(x, hdr, wk4, wv4, (float*)d_out);
}